// Round 7
// baseline (300.416 us; speedup 1.0000x reference)
//
#include <hip/hip_runtime.h>

// B=32, C=16, RES=128, NA=64
// out[b,0,a,i] = bias + sum_j bilinear(y[b],...), y[b] = sum_c w[c]*x[b,c]
//
// LDS element E[r][c] = (b0[r,c], b1[r,c]) as 2 x fp16 (4 B), 2-px zero guard.
// 72 KB LDS -> 2 blocks/CU; j-range split in two -> 512 blocks, 4 waves/SIMD.
// Taps: two ds_read2_b32 (offsets {0,1},{133,134}); interp: v_pk_fma_f16
// (batch-pair packed, broadcast fp16 weights), fp16 accum flushed to fp32
// every 8 j. Partials combined by f32 atomicAdd into memset-zeroed out.

#define B_    32
#define C_    16
#define RES   128
#define NA    64
#define SLDS  133              // row stride in 4-B elements (offset1 <= 255 ok)
#define ROWS  132
#define NELEM (ROWS * SLDS)    // 17556 elements
#define NPADE 18432            // padded: 18432*4 B = 73728 B = 512 thr * 9 uint4
#define NPAIR 16

typedef _Float16 half2v __attribute__((ext_vector_type(2)));

// ---------------- Kernel 1: channel reduce (HBM-bound, ~roofline) ----------------
__global__ __launch_bounds__(256) void chan_reduce(const float* __restrict__ x,
                                                   const float* __restrict__ w,
                                                   float* __restrict__ y) {
    int t  = blockIdx.x * 256 + threadIdx.x;
    int b  = t >> 12;
    int r4 = t & 4095;
    const float4* xb = (const float4*)(x + (size_t)b * C_ * RES * RES);
    float wr[C_];
#pragma unroll
    for (int c = 0; c < C_; ++c) wr[c] = w[c];
    float4 acc = make_float4(0.f, 0.f, 0.f, 0.f);
#pragma unroll
    for (int c = 0; c < C_; ++c) {
        float4 v = xb[c * (RES * RES / 4) + r4];
        acc.x = fmaf(wr[c], v.x, acc.x);
        acc.y = fmaf(wr[c], v.y, acc.y);
        acc.z = fmaf(wr[c], v.z, acc.z);
        acc.w = fmaf(wr[c], v.w, acc.w);
    }
    ((float4*)y)[(size_t)b * (RES * RES / 4) + r4] = acc;
}

// ---------------- Kernel 2: build guarded packed pair-images ----------------
// element (p, r, c) = (y[2p][r-2,c-2], y[2p+1][r-2,c-2]) as 2 x fp16;
// zeros on guard rows/cols and pad.
__global__ __launch_bounds__(256) void pack_pairs(const float* __restrict__ y,
                                                  unsigned int* __restrict__ pk) {
    int flat = blockIdx.x * 256 + threadIdx.x;   // 16*18432 = 294912
    int p    = flat / NPADE;
    int rem  = flat - p * NPADE;
    unsigned int val = 0u;
    if (rem < NELEM) {
        int r = rem / SLDS;
        int c = rem - r * SLDS;
        if (r >= 2 && r <= 129 && c >= 2 && c <= 129) {
            int q = r - 2, m = c - 2;
            const float* y0 = y + (size_t)(2 * p) * (RES * RES) + q * RES;
            const float* y1 = y0 + RES * RES;
            val = __builtin_bit_cast(unsigned int,
                      __builtin_amdgcn_cvt_pkrtz(y0[m], y1[m]));
        }
    }
    pk[flat] = val;
}

// ---------------- Kernel 3: radon, 2 batches/block, half j-range ----------------
// grid = 16 pairs x 16 grp x 2 jhalf = 512 blocks, 512 thr (4 waves/SIMD)
__global__ __launch_bounds__(512, 4) void radon_k(const unsigned int* __restrict__ pk,
                                                  const float* __restrict__ angles,
                                                  const float* __restrict__ bias,
                                                  float* __restrict__ out) {
    __shared__ unsigned int lds[NPADE];   // 73728 B -> 2 blocks/CU
    const int bid = blockIdx.x;
    const int h   = bid & 1;              // j-half
    const int grp = (bid >> 1) & 15;
    const int p   = bid >> 5;
    const int t   = threadIdx.x;

    // ---- branch-free bulk stage: 9 uint4 per thread ----
    {
        const uint4* src = (const uint4*)(pk + (size_t)p * NPADE);
        uint4*       dst = (uint4*)lds;
#pragma unroll
        for (int k = 0; k < 9; ++k) dst[k * 512 + t] = src[k * 512 + t];
    }
    __syncthreads();

    const int a = (t >> 7) * 16 + grp;    // wave-uniform angle (interleaved)
    const int i = t & 127;
    float th = angles[a];
    float s, c;
    __sincosf(th, &s, &c);

    const float ci = (float)i - 63.5f;
    const float j0 = (float)(h * 64);
    // X(j0+jf) = Xb + jf*(-s);  Y(j0+jf) = Yb + jf*c
    const float Xb = fmaf(ci, c, fmaf(63.5f - j0, s, 65.5f));
    const float Yb = fmaf(ci, s, fmaf(j0 - 63.5f, c, 65.5f));
    const float ns = -s;

    float accf0 = 0.f, accf1 = 0.f;
#pragma unroll
    for (int o = 0; o < 8; ++o) {
        half2v accA = (half2v)0, accB = (half2v)0;   // (b0, b1) fp16 partials
#pragma unroll
        for (int u8 = 0; u8 < 8; ++u8) {
            float jf = (float)(o * 8 + u8);
            float X  = fmaf(jf, ns, Xb);
            float Y  = fmaf(jf, c,  Yb);
            float fx = floorf(X), fy = floorf(Y);
            float wx = X - fx,    wy = Y - fy;
            float gx = fminf(fmaxf(fx, 0.f), 130.f);    // v_med3_f32
            float gy = fminf(fmaxf(fy, 0.f), 130.f);
            int addr = (int)fmaf(gy, (float)SLDS, gx);  // exact (< 2^24)
            unsigned int q00 = lds[addr],        q01 = lds[addr + 1];        // ds_read2_b32
            unsigned int q10 = lds[addr + SLDS], q11 = lds[addr + SLDS + 1]; // ds_read2_b32
            float un = 1.f - wx;
            float A0 = 1.f - wy;
            half2v w00 = __builtin_bit_cast(half2v, __builtin_amdgcn_cvt_pkrtz(A0 * un, A0 * un));
            half2v w01 = __builtin_bit_cast(half2v, __builtin_amdgcn_cvt_pkrtz(A0 * wx, A0 * wx));
            half2v w10 = __builtin_bit_cast(half2v, __builtin_amdgcn_cvt_pkrtz(wy * un, wy * un));
            half2v w11 = __builtin_bit_cast(half2v, __builtin_amdgcn_cvt_pkrtz(wy * wx, wy * wx));
            accA = __builtin_elementwise_fma(__builtin_bit_cast(half2v, q00), w00, accA);
            accA = __builtin_elementwise_fma(__builtin_bit_cast(half2v, q01), w01, accA);
            accB = __builtin_elementwise_fma(__builtin_bit_cast(half2v, q10), w10, accB);
            accB = __builtin_elementwise_fma(__builtin_bit_cast(half2v, q11), w11, accB);
        }
        half2v accp = accA + accB;
        accf0 += (float)accp.x;
        accf1 += (float)accp.y;
    }

    float bv = (h == 0) ? bias[0] : 0.f;
    atomicAdd(&out[(2 * p)     * (NA * RES) + a * RES + i], accf0 + bv);
    atomicAdd(&out[(2 * p + 1) * (NA * RES) + a * RES + i], accf1 + bv);
}

extern "C" void kernel_launch(void* const* d_in, const int* in_sizes, int n_in,
                              void* d_out, int out_size, void* d_ws, size_t ws_size,
                              hipStream_t stream) {
    const float* x      = (const float*)d_in[0];   // 32*16*128*128
    const float* angles = (const float*)d_in[1];   // 64
    const float* w      = (const float*)d_in[2];   // 16
    const float* bias   = (const float*)d_in[3];   // 1
    float* out = (float*)d_out;                    // 32*64*128 fp32

    float*        y  = (float*)d_ws;                                   // 2 MiB
    unsigned int* pk = (unsigned int*)((char*)d_ws + (size_t)4 * 1024 * 1024);

    hipMemsetAsync(out, 0, (size_t)out_size * sizeof(float), stream);  // capture-safe
    chan_reduce<<<dim3(512), dim3(256), 0, stream>>>(x, w, y);
    pack_pairs<<<dim3(NPAIR * NPADE / 256), dim3(256), 0, stream>>>(y, pk);
    radon_k<<<dim3(NPAIR * 16 * 2), dim3(512), 0, stream>>>(pk, angles, bias, out);
}

// Round 8
// 96.848 us; speedup vs baseline: 3.1019x; 3.1019x over previous
//
#include <hip/hip_runtime.h>

// B=32, C=16, RES=128, NA=64
// out[b,0,a,i] = bias + sum_j bilinear(y[b],...), y[b] = sum_c w[c]*x[b,c]
//
// FRONT-END (fused): one kernel computes the channel-reduced row for both
// batches of a pair and emits the guarded packed pair-row directly:
//   pk element (p,r,c) = (y0[r-2,c-2], y0[r-2,c-1], y1[r-2,c-2], y1[r-2,c-1])
//   as 4 x fp16 (8 B), zeros on the 2-px guard band and pad.
// RADON (identical to the proven Round-6 kernel): 2 batches/block, LDS-resident
// packed image, ONE ds_read2_b64 per sample-pair feeding 4 x v_dot2_f32_f16.

#define B_    32
#define C_    16
#define RES   128
#define NA    64
#define SLDS  133              // row stride in 8-B elements (ds_read2_b64 offset1=133 <= 255)
#define ROWS  132
#define NELEM (ROWS * SLDS)    // 17556 elements
#define NPAD  18432            // padded: 18432*8 B = 147456 B = 512 thr * 18 uint4
#define NPAIR 16

typedef _Float16 half2v __attribute__((ext_vector_type(2)));

// ---------------- Kernel 1: fused channel-reduce + guarded pair-pack ----------------
// grid = 16 pairs x 128 rows = 2048 blocks, 256 threads
// thread t: batch-in-pair u = t>>7, col m = t&127
__global__ __launch_bounds__(256) void chanpack(const float* __restrict__ x,
                                                const float* __restrict__ w,
                                                uint2* __restrict__ pk) {
    const int blk = blockIdx.x;
    const int p   = blk >> 7;          // pair
    const int q   = blk & 127;         // image row
    const int t   = threadIdx.x;
    const int u   = t >> 7;            // batch within pair
    const int m   = t & 127;           // column

    __shared__ float rowbuf[2][130];   // y[k] at [u][k+1]; [u][0]=[u][129]=0

    float wr[C_];
#pragma unroll
    for (int c = 0; c < C_; ++c) wr[c] = w[c];

    const float* xb = x + ((size_t)(2 * p + u) * C_) * (RES * RES) + q * RES + m;
    float acc = 0.f;
#pragma unroll
    for (int c = 0; c < C_; ++c) acc = fmaf(wr[c], xb[c * (RES * RES)], acc);

    rowbuf[u][m + 1] = acc;
    if (m == 0) { rowbuf[u][0] = 0.f; rowbuf[u][129] = 0.f; }
    __syncthreads();

    // emit packed row r = q+2 (133 elements); nonzero for c in [1..129]:
    // taps y[c-2], y[c-1] live at rowbuf[][c-1], rowbuf[][c]
    uint2* dst = pk + (size_t)p * NPAD + (q + 2) * SLDS;
    if (t < SLDS) {
        int c = t;
        uint2 v = make_uint2(0u, 0u);
        if (c >= 1 && c <= 129) {
            v.x = __builtin_bit_cast(unsigned int,
                      __builtin_amdgcn_cvt_pkrtz(rowbuf[0][c - 1], rowbuf[0][c]));
            v.y = __builtin_bit_cast(unsigned int,
                      __builtin_amdgcn_cvt_pkrtz(rowbuf[1][c - 1], rowbuf[1][c]));
        }
        dst[c] = v;
    }

    // q==0 blocks zero the guard rows (0,1,130,131) and the pad tail
    if (q == 0) {
        uint2* base = pk + (size_t)p * NPAD;
        const uint2 z = make_uint2(0u, 0u);
        for (int k = t; k < 2 * SLDS; k += 256) {          // rows 0,1
            base[k] = z;
            base[130 * SLDS + k] = z;                       // rows 130,131
        }
        for (int k = t; k < NPAD - NELEM; k += 256)         // pad tail
            base[NELEM + k] = z;
    }
}

// ---------------- Kernel 2: radon, 2 batches per block (Round-6 verbatim) ----------------
// grid = 16 pairs x 16 groups = 256 blocks, 512 threads
__global__ __launch_bounds__(512) void radon_k(const uint2* __restrict__ pk,
                                               const float* __restrict__ angles,
                                               const float* __restrict__ bias,
                                               float* __restrict__ out) {
    __shared__ uint2 lds[NPAD];   // 147456 B
    const int bid = blockIdx.x;
    const int p   = bid >> 4;
    const int grp = bid & 15;
    const int t   = threadIdx.x;

    // ---- branch-free bulk stage: 18 uint4 per thread, guards included ----
    {
        const uint4* src = (const uint4*)(pk + (size_t)p * NPAD);
        uint4*       dst = (uint4*)lds;
#pragma unroll
        for (int k = 0; k < 18; ++k) dst[k * 512 + t] = src[k * 512 + t];
    }
    __syncthreads();

    const int a = (t >> 7) * 16 + grp;     // wave-uniform angle
    const int i = t & 127;
    float th = angles[a];
    float s, c;
    __sincosf(th, &s, &c);

    const float ci = (float)i - 63.5f;
    const float Xb = fmaf(ci, c, fmaf(63.5f, s, 65.5f));
    const float Yb = fmaf(ci, s, fmaf(-63.5f, c, 65.5f));
    const float ns = -s;

    float acc00 = 0.f, acc01 = 0.f, acc10 = 0.f, acc11 = 0.f;
#pragma unroll 8
    for (int j = 0; j < RES; ++j) {
        float jf = (float)j;
        float X  = fmaf(jf, ns, Xb);
        float Y  = fmaf(jf, c,  Yb);
        float fx = floorf(X), fy = floorf(Y);
        float wx = X - fx,    wy = Y - fy;
        float gx = fminf(fmaxf(fx, 0.f), 130.f);    // v_med3_f32
        float gy = fminf(fmaxf(fy, 0.f), 130.f);
        int addr = (int)fmaf(gy, (float)SLDS, gx);  // exact (< 2^24)
        uint2 q0 = lds[addr];                       // row gy:   (b0 pair, b1 pair)
        uint2 q1 = lds[addr + SLDS];                // row gy+1  — ds_read2_b64
        float un = 1.f - wx;
        float A0 = 1.f - wy;
        half2v wa = __builtin_bit_cast(half2v, __builtin_amdgcn_cvt_pkrtz(A0 * un, A0 * wx));
        half2v wb = __builtin_bit_cast(half2v, __builtin_amdgcn_cvt_pkrtz(wy * un, wy * wx));
        acc00 = __builtin_amdgcn_fdot2(__builtin_bit_cast(half2v, q0.x), wa, acc00, false);
        acc10 = __builtin_amdgcn_fdot2(__builtin_bit_cast(half2v, q0.y), wa, acc10, false);
        acc01 = __builtin_amdgcn_fdot2(__builtin_bit_cast(half2v, q1.x), wb, acc01, false);
        acc11 = __builtin_amdgcn_fdot2(__builtin_bit_cast(half2v, q1.y), wb, acc11, false);
    }

    float bv = bias[0];
    out[(2 * p)     * (NA * RES) + a * RES + i] = (acc00 + acc01) + bv;
    out[(2 * p + 1) * (NA * RES) + a * RES + i] = (acc10 + acc11) + bv;
}

extern "C" void kernel_launch(void* const* d_in, const int* in_sizes, int n_in,
                              void* d_out, int out_size, void* d_ws, size_t ws_size,
                              hipStream_t stream) {
    const float* x      = (const float*)d_in[0];   // 32*16*128*128
    const float* angles = (const float*)d_in[1];   // 64
    const float* w      = (const float*)d_in[2];   // 16
    const float* bias   = (const float*)d_in[3];   // 1
    float* out = (float*)d_out;                    // 32*64*128 fp32

    uint2* pk = (uint2*)d_ws;                      // 16*18432*8 B = 2.36 MiB

    chanpack<<<dim3(NPAIR * RES), dim3(256), 0, stream>>>(x, w, pk);
    radon_k<<<dim3(NPAIR * 16), dim3(512), 0, stream>>>(pk, angles, bias, out);
}

// Round 9
// 96.832 us; speedup vs baseline: 3.1024x; 1.0002x over previous
//
#include <hip/hip_runtime.h>

// B=32, C=16, RES=128, NA=64
// out[b,0,a,i] = bias + sum_j bilinear(y[b],...), y[b] = sum_c w[c]*x[b,c]
//
// FRONT-END (fused, Round-8): chanpack computes channel-reduced rows for a
// batch pair and emits the guarded packed pair-row:
//   pk(p,r,c) = (y0[r-2,c-2], y0[r-2,c-1], y1[r-2,c-2], y1[r-2,c-1]) 4xfp16.
// RADON (Round-6 structure + R9 changes): 2 batches/block, LDS-resident
// packed image, ONE ds_read2_b64 per sample-pair, 4 x v_dot2_f32_f16.
// R9: depth-2 software pipeline on the LDS loads (addr->read hoisted one
// iteration ahead of use) + packed-fp16 weight math (pk_fma/pk_mul vs
// 6 scalar f32 ops).

#define B_    32
#define C_    16
#define RES   128
#define NA    64
#define SLDS  133              // row stride in 8-B elements (ds_read2_b64 offset1=133 <= 255)
#define ROWS  132
#define NELEM (ROWS * SLDS)    // 17556 elements
#define NPAD  18432            // padded: 18432*8 B = 147456 B = 512 thr * 18 uint4
#define NPAIR 16

typedef _Float16 half2v __attribute__((ext_vector_type(2)));

// ---------------- Kernel 1: fused channel-reduce + guarded pair-pack ----------------
// grid = 16 pairs x 128 rows, 256 threads; t: u = t>>7 (batch), m = t&127 (col)
__global__ __launch_bounds__(256) void chanpack(const float* __restrict__ x,
                                                const float* __restrict__ w,
                                                uint2* __restrict__ pk) {
    const int blk = blockIdx.x;
    const int p   = blk >> 7;          // pair
    const int q   = blk & 127;         // image row
    const int t   = threadIdx.x;
    const int u   = t >> 7;            // batch within pair
    const int m   = t & 127;           // column

    __shared__ float rowbuf[2][130];   // y[k] at [u][k+1]; [u][0]=[u][129]=0

    float wr[C_];
#pragma unroll
    for (int c = 0; c < C_; ++c) wr[c] = w[c];

    const float* xb = x + ((size_t)(2 * p + u) * C_) * (RES * RES) + q * RES + m;
    float acc = 0.f;
#pragma unroll
    for (int c = 0; c < C_; ++c) acc = fmaf(wr[c], xb[c * (RES * RES)], acc);

    rowbuf[u][m + 1] = acc;
    if (m == 0) { rowbuf[u][0] = 0.f; rowbuf[u][129] = 0.f; }
    __syncthreads();

    // packed row r = q+2; nonzero for c in [1..129]
    uint2* dst = pk + (size_t)p * NPAD + (q + 2) * SLDS;
    if (t < SLDS) {
        int c = t;
        uint2 v = make_uint2(0u, 0u);
        if (c >= 1 && c <= 129) {
            v.x = __builtin_bit_cast(unsigned int,
                      __builtin_amdgcn_cvt_pkrtz(rowbuf[0][c - 1], rowbuf[0][c]));
            v.y = __builtin_bit_cast(unsigned int,
                      __builtin_amdgcn_cvt_pkrtz(rowbuf[1][c - 1], rowbuf[1][c]));
        }
        dst[c] = v;
    }

    // q==0 blocks zero the guard rows (0,1,130,131) and the pad tail
    if (q == 0) {
        uint2* base = pk + (size_t)p * NPAD;
        const uint2 z = make_uint2(0u, 0u);
        for (int k = t; k < 2 * SLDS; k += 256) {
            base[k] = z;
            base[130 * SLDS + k] = z;
        }
        for (int k = t; k < NPAD - NELEM; k += 256)
            base[NELEM + k] = z;
    }
}

// ---------------- Kernel 2: radon, 2 batches per block ----------------
// grid = 16 pairs x 16 groups = 256 blocks, 512 threads
__global__ __launch_bounds__(512) void radon_k(const uint2* __restrict__ pk,
                                               const float* __restrict__ angles,
                                               const float* __restrict__ bias,
                                               float* __restrict__ out) {
    __shared__ uint2 lds[NPAD];   // 147456 B
    const int bid = blockIdx.x;
    const int p   = bid >> 4;
    const int grp = bid & 15;
    const int t   = threadIdx.x;

    // ---- branch-free bulk stage: 18 uint4 per thread, guards included ----
    {
        const uint4* src = (const uint4*)(pk + (size_t)p * NPAD);
        uint4*       dst = (uint4*)lds;
#pragma unroll
        for (int k = 0; k < 18; ++k) dst[k * 512 + t] = src[k * 512 + t];
    }
    __syncthreads();

    const int a = (t >> 7) * 16 + grp;     // wave-uniform angle
    const int i = t & 127;
    float th = angles[a];
    float s, c;
    __sincosf(th, &s, &c);

    const float ci = (float)i - 63.5f;
    const float Xb = fmaf(ci, c, fmaf(63.5f, s, 65.5f));
    const float Yb = fmaf(ci, s, fmaf(-63.5f, c, 65.5f));
    const float ns = -s;

    // packed-fp16 weight constants: uw = pk_fma(h, kM1P1, kP1Z) = (1-w, w)
    const half2v kM1P1 = half2v{(_Float16)(-1.f), (_Float16)(1.f)};
    const half2v kP1Z  = half2v{(_Float16)( 1.f), (_Float16)(0.f)};

    // address for iteration j (hoisted one step ahead of use)
    auto addr_of = [&](float jf) -> int {
        float X  = fmaf(jf, ns, Xb);
        float Y  = fmaf(jf, c,  Yb);
        float gx = fminf(fmaxf(floorf(X), 0.f), 130.f);
        float gy = fminf(fmaxf(floorf(Y), 0.f), 130.f);
        return (int)fmaf(gy, (float)SLDS, gx);      // exact (< 2^24)
    };

    float acc00 = 0.f, acc01 = 0.f, acc10 = 0.f, acc11 = 0.f;

    int   addr = addr_of(0.f);
    uint2 q0 = lds[addr];                   // prologue loads for j=0
    uint2 q1 = lds[addr + SLDS];

#pragma unroll 8
    for (int j = 0; j < RES; ++j) {
        float jf = (float)j;
        // recompute current coords (cheap) for the fractional weights
        float X  = fmaf(jf, ns, Xb);
        float Y  = fmaf(jf, c,  Yb);
        float wx = X - floorf(X);
        float wy = Y - floorf(Y);

        // ---- issue next iteration's loads before consuming current ----
        uint2 q0n, q1n;
        if (j < RES - 1) {
            int an = addr_of(jf + 1.f);
            q0n = lds[an];
            q1n = lds[an + SLDS];
        }

        half2v hwx = __builtin_bit_cast(half2v, __builtin_amdgcn_cvt_pkrtz(wx, wx));
        half2v hwy = __builtin_bit_cast(half2v, __builtin_amdgcn_cvt_pkrtz(wy, wy));
        half2v uwx = __builtin_elementwise_fma(hwx, kM1P1, kP1Z);  // (1-wx, wx)
        half2v uwy = __builtin_elementwise_fma(hwy, kM1P1, kP1Z);  // (1-wy, wy)
        half2v wa  = uwx * __builtin_shufflevector(uwy, uwy, 0, 0); // *(1-wy)
        half2v wb  = uwx * __builtin_shufflevector(uwy, uwy, 1, 1); // *wy

        acc00 = __builtin_amdgcn_fdot2(__builtin_bit_cast(half2v, q0.x), wa, acc00, false);
        acc10 = __builtin_amdgcn_fdot2(__builtin_bit_cast(half2v, q0.y), wa, acc10, false);
        acc01 = __builtin_amdgcn_fdot2(__builtin_bit_cast(half2v, q1.x), wb, acc01, false);
        acc11 = __builtin_amdgcn_fdot2(__builtin_bit_cast(half2v, q1.y), wb, acc11, false);

        q0 = q0n; q1 = q1n;
    }

    float bv = bias[0];
    out[(2 * p)     * (NA * RES) + a * RES + i] = (acc00 + acc01) + bv;
    out[(2 * p + 1) * (NA * RES) + a * RES + i] = (acc10 + acc11) + bv;
}

extern "C" void kernel_launch(void* const* d_in, const int* in_sizes, int n_in,
                              void* d_out, int out_size, void* d_ws, size_t ws_size,
                              hipStream_t stream) {
    const float* x      = (const float*)d_in[0];   // 32*16*128*128
    const float* angles = (const float*)d_in[1];   // 64
    const float* w      = (const float*)d_in[2];   // 16
    const float* bias   = (const float*)d_in[3];   // 1
    float* out = (float*)d_out;                    // 32*64*128 fp32

    uint2* pk = (uint2*)d_ws;                      // 16*18432*8 B = 2.36 MiB

    chanpack<<<dim3(NPAIR * RES), dim3(256), 0, stream>>>(x, w, pk);
    radon_k<<<dim3(NPAIR * 16), dim3(512), 0, stream>>>(pk, angles, bias, out);
}